// Round 1
// baseline (138.314 us; speedup 1.0000x reference)
//
#include <hip/hip_runtime.h>
#include <cstdint>

// Shapes fixed by the harness:
// u, delta, z: (b=2, d=1024, l=2048) fp32; A: (d, n=16); B, C: (b, n, l); D: (d,)
constexpr int kD = 1024;
constexpr int kN = 16;
constexpr int kL = 2048;
constexpr int BLOCK = 512;
constexpr int T  = kL / BLOCK;   // 4 timesteps per thread (one float4)
constexpr int NW = BLOCK / 64;   // 8 waves per block
constexpr int NH = 8;            // states per half (kN/2)
constexpr float LOG2E = 1.44269504088896340736f;

__device__ __forceinline__ float fast_exp2(float x) { return __builtin_amdgcn_exp2f(x); }
__device__ __forceinline__ float fast_exp(float x)  { return __builtin_amdgcn_exp2f(x * LOG2E); }
__device__ __forceinline__ float softplus_f(float x) {
  return (x > 20.0f) ? x : __logf(1.0f + fast_exp(x));
}

// DPP move with explicit 'old' (identity) — used only for the lane-exclusive
// prefix in the apply phase (16 uses/thread).
template<int CTRL, int RM>
__device__ __forceinline__ float dppf(float old_, float src) {
  union U { float f; int i; };
  U o, s, r; o.f = old_; s.f = src;
  r.i = __builtin_amdgcn_update_dpp(o.i, s.i, CTRL, RM, 0xF, false);
  return r.f;
}

__device__ __forceinline__ float readlane_f(float v, int l) {
  union U { float f; int i; };
  U a, r; a.f = v;
  r.i = __builtin_amdgcn_readlane(a.i, l);
  return r.f;
}

// Uniform-base + u32 byte-offset load: encourages global_load_dwordx4 v,voff,s[base]
__device__ __forceinline__ float4 ldg4(const char* base, uint32_t off) {
  return *reinterpret_cast<const float4*>(base + off);
}

// R12: hot 64-lane scan in raw DPP asm. bound_ctrl off + row_mask => invalid
// lanes DON'T WRITE dest, so in-place
//   v_fmac_f32_dpp x, x, a   (x += dpp(x)*a; boundary lanes keep x)
//   v_mul_f32_dpp  a, a, a   (a *= dpp(a);   boundary lanes keep a)
// is one masked Hillis-Steele step in 2 insts/state. State-inner interleave
// gives 16-inst spacing for the VALU->DPP hazard; s_nop 1 covers entry.
#define SCAN_FM(X, A, CTRL) \
  "v_fmac_f32_dpp " X ", " X ", " A " " CTRL "\n\t" \
  "v_mul_f32_dpp "  A ", " A ", " A " " CTRL "\n\t"
#define SCAN_STEP(CTRL) \
  SCAN_FM("%0","%8",CTRL)  SCAN_FM("%1","%9",CTRL)  \
  SCAN_FM("%2","%10",CTRL) SCAN_FM("%3","%11",CTRL) \
  SCAN_FM("%4","%12",CTRL) SCAN_FM("%5","%13",CTRL) \
  SCAN_FM("%6","%14",CTRL) SCAN_FM("%7","%15",CTRL)

// Single-arg launch_bounds ONLY: any min-waves hint triggers a spill cascade
// (R2: 48 VGPR + 350 MB scratch; R3: 64 VGPR + 260 MB; R6: 1024-thr cap).
__global__ __launch_bounds__(BLOCK)
void selscan_kernel(const float* __restrict__ u,  const float* __restrict__ dl,
                    const float* __restrict__ A,  const float* __restrict__ Bm,
                    const float* __restrict__ Cm, const float* __restrict__ Dv,
                    const float* __restrict__ zm, float* __restrict__ out)
{
  const int row  = blockIdx.x;          // b*kD + d
  const int b    = row >> 10;           // kD = 1024
  const int d    = row & (kD - 1);
  const int tid  = threadIdx.x;
  const int lane = tid & 63;
  const int wid  = tid >> 6;
  const uint32_t toff = (uint32_t)tid * 16u;     // this thread's float4, bytes

  const char* ub = (const char*)(u  + (size_t)row * kL);
  const char* db = (const char*)(dl + (size_t)row * kL);
  const char* Bb = (const char*)(Bm + (size_t)b * kN * kL);
  const char* Cb = (const char*)(Cm + (size_t)b * kN * kL);

  // A row is block-uniform -> scalar loads (SGPRs). LOG2E is folded into
  // spl[] (4 muls once) instead of pre-scaling A (was 16 VGPR-muls).
  const float* Arow = A + (size_t)d * kN;

  // Prefetch half-0/state-0 B,C tiles: issued here so their L2 latency
  // overlaps the u/delta HBM load + softplus prologue.
  float4 bcur = ldg4(Bb, toff);
  float4 ccur = ldg4(Cb, toff);

  // Per-thread chunk [tid*T, tid*T+T): u, sp*u, sp*LOG2E in regs.
  float uu[T], spl[T], du[T];
  {
    float4 a0 = *reinterpret_cast<const float4*>(ub + toff);
    uu[0]=a0.x; uu[1]=a0.y; uu[2]=a0.z; uu[3]=a0.w;
    float4 b0 = *reinterpret_cast<const float4*>(db + toff);
    float dv[T] = {b0.x, b0.y, b0.z, b0.w};
    #pragma unroll
    for (int i = 0; i < T; ++i) {
      float s = softplus_f(dv[i]);
      du[i]  = s * uu[i];
      spl[i] = s * LOG2E;              // exp2 arg = spl*A == sp*LOG2E*A
    }
  }

  float y[T];
  #pragma unroll
  for (int i = 0; i < T; ++i) y[i] = 0.0f;

  // Per-half wave-total buffers: (a,x) per (wave, state). 2*8*8*8B = 1 KB.
  // Separate buffer per half -> no end-of-half barrier needed.
  __shared__ float2 sAX[2][NW][NH];

  #pragma unroll 1                      // halves sequential: live-range control
  for (int half = 0; half < 2; ++half) {
    // Per-half A scalars: uniform address (half is a uniform loop index),
    // compile-time inner index -> stays SGPR-resident, no scratch (rule #20).
    float Ah[NH];
    #pragma unroll
    for (int j = 0; j < NH; ++j) Ah[j] = Arow[half * NH + j];

    const char* Bh = Bb + (uint32_t)half * (uint32_t)(NH * kL * 4);  // +64 KB
    const char* Ch = Cb + (uint32_t)half * (uint32_t)(NH * kL * 4);

    // ---- Pass A with the cp-trick: C consumed at load time.
    // h_i = pp_i*h0 + hl_i (linearity) =>  y_i += C_i*hl_i here,
    // cp_i = C_i*pp_i saved; post-scan apply is pure register FMA.
    // B/C register-double-buffered one state ahead; the n==NH-1 prefetch of
    // half 0 fetches half 1's first tile (noff lands exactly on the next
    // half's base), hiding it under scan+fold+apply.
    float cp[NH][T];
    float cA[NH], cX[NH];
    #pragma unroll
    for (int n = 0; n < NH; ++n) {
      float4 bnxt, cnxt;
      const uint32_t noff = (uint32_t)(n + 1) * (uint32_t)(kL * 4) + toff;
      if (n < NH - 1 || half == 0) {     // n<7: always; n==7: uniform branch
        bnxt = ldg4(Bh, noff);
        cnxt = ldg4(Ch, noff);
      }
      const float Arn = Ah[n];           // SGPR operand of the exp-arg mul
      float Bv[T] = {bcur.x, bcur.y, bcur.z, bcur.w};
      float Cv[T] = {ccur.x, ccur.y, ccur.z, ccur.w};
      float h = 0.0f, p = 1.0f;
      #pragma unroll
      for (int i = 0; i < T; ++i) {
        float a = fast_exp2(spl[i] * Arn);
        h = a * h + du[i] * Bv[i];
        p *= a;
        y[i] += Cv[i] * h;
        cp[n][i] = Cv[i] * p;
      }
      cA[n] = p; cX[n] = h;
      if (n < NH - 1 || half == 0) { bcur = bnxt; ccur = cnxt; }
    }

    // ---- Wave-level scan on chunk aggregates — raw DPP, 2 inst/state/step.
    {
      float x0=cX[0], x1=cX[1], x2=cX[2], x3=cX[3],
            x4=cX[4], x5=cX[5], x6=cX[6], x7=cX[7];
      float a0=cA[0], a1=cA[1], a2=cA[2], a3=cA[3],
            a4=cA[4], a5=cA[5], a6=cA[6], a7=cA[7];
      asm("s_nop 1\n\t"
          SCAN_STEP("row_shr:1 row_mask:0xf bank_mask:0xf")
          SCAN_STEP("row_shr:2 row_mask:0xf bank_mask:0xf")
          SCAN_STEP("row_shr:4 row_mask:0xf bank_mask:0xf")
          SCAN_STEP("row_shr:8 row_mask:0xf bank_mask:0xf")
          SCAN_STEP("row_bcast:15 row_mask:0xa bank_mask:0xf")
          SCAN_STEP("row_bcast:31 row_mask:0xc bank_mask:0xf")
          : "+v"(x0), "+v"(x1), "+v"(x2), "+v"(x3),
            "+v"(x4), "+v"(x5), "+v"(x6), "+v"(x7),
            "+v"(a0), "+v"(a1), "+v"(a2), "+v"(a3),
            "+v"(a4), "+v"(a5), "+v"(a6), "+v"(a7));
      cX[0]=x0; cX[1]=x1; cX[2]=x2; cX[3]=x3;
      cX[4]=x4; cX[5]=x5; cX[6]=x6; cX[7]=x7;
      cA[0]=a0; cA[1]=a1; cA[2]=a2; cA[3]=a3;
      cA[4]=a4; cA[5]=a5; cA[6]=a6; cA[7]=a7;
    }

    // ---- Publish wave totals (lane 63 holds them), ONE barrier.
    if (lane == 63) {
      #pragma unroll
      for (int n = 0; n < NH; ++n) sAX[half][wid][n] = make_float2(cA[n], cX[n]);
    }
    __syncthreads();

    // ---- Parallel exclusive fold (replaces the serial w2<wid loop, which
    // was up to 7 DEPENDENT LDS-load->fma round-trips): all 7 candidate
    // aggregates load concurrently (one lgkm wait, 8-way same-address
    // broadcast per lane group = conflict-free), then an identity-padded
    // select+fma chain. wid is wave-uniform; order matches the old loop:
    // ex = x[wid-1] + a[wid-1]*(x[wid-2] + ...), identities are no-ops.
    float ex = 0.0f;                     // lane n<8: exclusive x-prefix, state n
    {
      const int n = lane & 7;
      float2 s[NW - 1];
      #pragma unroll
      for (int w2 = 0; w2 < NW - 1; ++w2) s[w2] = sAX[half][w2][n];
      #pragma unroll
      for (int w2 = 0; w2 < NW - 1; ++w2) {
        float aa = (w2 < wid) ? s[w2].x : 1.0f;
        float xx = (w2 < wid) ? s[w2].y : 0.0f;
        ex = aa * ex + xx;
      }
    }

    // ---- Apply: y_i += cp_i * h0   (pure FMA; exn broadcast via readlane)
    #pragma unroll
    for (int n = 0; n < NH; ++n) {
      float al = dppf<0x138,0xF>(1.0f, cA[n]);   // lane-exclusive prefix
      float xl = dppf<0x138,0xF>(0.0f, cX[n]);
      float exn = readlane_f(ex, n);             // scalar: wave-exclusive x
      float h0 = al * exn + xl;                  // state entering this chunk
      #pragma unroll
      for (int i = 0; i < T; ++i) y[i] += cp[n][i] * h0;
    }
    // no end-of-half barrier: half 1 uses its own sAX buffer
  }

  // ---- Epilogue: + u*D, * silu(z), store  (uu kept in regs)
  const float Dd = Dv[d];
  const char* zb = (const char*)(zm + (size_t)row * kL);
  float4 z0 = *reinterpret_cast<const float4*>(zb + toff);
  float zv[T] = {z0.x, z0.y, z0.z, z0.w};
  float ov[T];
  #pragma unroll
  for (int i = 0; i < T; ++i) {
    float yy  = y[i] + uu[i] * Dd;
    float sig = 1.0f / (1.0f + fast_exp(-zv[i]));
    ov[i] = yy * zv[i] * sig;
  }
  char* ob = (char*)(out + (size_t)row * kL);
  *reinterpret_cast<float4*>(ob + toff) = make_float4(ov[0], ov[1], ov[2], ov[3]);
}

extern "C" void kernel_launch(void* const* d_in, const int* in_sizes, int n_in,
                              void* d_out, int out_size, void* d_ws, size_t ws_size,
                              hipStream_t stream)
{
  const float* u  = (const float*)d_in[0];
  const float* dl = (const float*)d_in[1];
  const float* A  = (const float*)d_in[2];
  const float* Bm = (const float*)d_in[3];
  const float* Cm = (const float*)d_in[4];
  const float* Dv = (const float*)d_in[5];
  const float* zm = (const float*)d_in[6];
  float* out = (float*)d_out;
  const int rows = in_sizes[0] / kL;   // b*d = 2048
  selscan_kernel<<<rows, BLOCK, 0, stream>>>(u, dl, A, Bm, Cm, Dv, zm, out);
}

// Round 2
// 126.497 us; speedup vs baseline: 1.0934x; 1.0934x over previous
//
#include <hip/hip_runtime.h>
#include <cstdint>

// Shapes fixed by the harness:
// u, delta, z: (b=2, d=1024, l=2048) fp32; A: (d, n=16); B, C: (b, n, l); D: (d,)
constexpr int kD = 1024;
constexpr int kN = 16;
constexpr int kL = 2048;
constexpr int BLOCK = 512;
constexpr int T  = kL / BLOCK;   // 4 timesteps per thread (one float4)
constexpr int NW = BLOCK / 64;   // 8 waves per block
constexpr int NQ = 4;            // states per pass (quarter of kN)
constexpr int NP = kN / NQ;      // 4 passes
constexpr float LOG2E = 1.44269504088896340736f;

__device__ __forceinline__ float fast_exp2(float x) { return __builtin_amdgcn_exp2f(x); }
__device__ __forceinline__ float fast_exp(float x)  { return __builtin_amdgcn_exp2f(x * LOG2E); }
__device__ __forceinline__ float softplus_f(float x) {
  return (x > 20.0f) ? x : __logf(1.0f + fast_exp(x));
}

// DPP move with explicit 'old' (identity) — used only for the lane-exclusive
// prefix in the apply phase.
template<int CTRL, int RM>
__device__ __forceinline__ float dppf(float old_, float src) {
  union U { float f; int i; };
  U o, s, r; o.f = old_; s.f = src;
  r.i = __builtin_amdgcn_update_dpp(o.i, s.i, CTRL, RM, 0xF, false);
  return r.f;
}

__device__ __forceinline__ float readlane_f(float v, int l) {
  union U { float f; int i; };
  U a, r; a.f = v;
  r.i = __builtin_amdgcn_readlane(a.i, l);
  return r.f;
}

// R12: hot 64-lane scan in raw DPP asm. bound_ctrl off + row_mask => invalid
// lanes DON'T WRITE dest, so in-place
//   v_fmac_f32_dpp x, x, a   (x += dpp(x)*a; boundary lanes keep x)
//   v_mul_f32_dpp  a, a, a   (a *= dpp(a);   boundary lanes keep a)
// is one masked Hillis-Steele step in 2 insts/state. State-inner interleave
// gives 8-inst spacing for the VALU->DPP hazard (needs ~2); s_nop 1 covers entry.
#define SCAN_FM(X, A, CTRL) \
  "v_fmac_f32_dpp " X ", " X ", " A " " CTRL "\n\t" \
  "v_mul_f32_dpp "  A ", " A ", " A " " CTRL "\n\t"
#define SCAN_STEP(CTRL) \
  SCAN_FM("%0","%4",CTRL) SCAN_FM("%1","%5",CTRL) \
  SCAN_FM("%2","%6",CTRL) SCAN_FM("%3","%7",CTRL)

// Single-arg launch_bounds ONLY: any min-waves hint triggers a spill cascade
// (R2: 48 VGPR + 350 MB scratch; R3: 64 VGPR + 260 MB; R6: 1024-thr cap).
// Occupancy is instead raised STRUCTURALLY: 4 passes of 4 states (was 2x8)
// cuts peak live state (cp 32->16, cA/cX 16->8, uu dropped) to cross the
// <=85-VGPR cliff -> 6 waves/SIMD -> 3 blocks/CU.
__global__ __launch_bounds__(BLOCK)
void selscan_kernel(const float* __restrict__ u,  const float* __restrict__ dl,
                    const float* __restrict__ A,  const float* __restrict__ Bm,
                    const float* __restrict__ Cm, const float* __restrict__ Dv,
                    const float* __restrict__ zm, float* __restrict__ out)
{
  const int row  = blockIdx.x;          // b*kD + d
  const int b    = row >> 10;           // kD = 1024
  const int d    = row & (kD - 1);
  const int tid  = threadIdx.x;
  const int lane = tid & 63;
  const int wid  = tid >> 6;

  const size_t roff = (size_t)row * kL;
  const float4* u4 = reinterpret_cast<const float4*>(u  + roff);
  const float4* d4 = reinterpret_cast<const float4*>(dl + roff);

  // Per-thread chunk [tid*T, tid*T+T): softplus(delta)*LOG2E and delta*u in
  // regs. u itself is NOT carried — re-loaded in the epilogue (frees 4 VGPRs
  // across the whole main body; the re-load is an L2/LLC hit under the last
  // apply phase).
  float spl[T], du[T];
  {
    float4 a0 = u4[tid];
    float4 b0 = d4[tid];
    float uv[T] = {a0.x, a0.y, a0.z, a0.w};
    float dv[T] = {b0.x, b0.y, b0.z, b0.w};
    #pragma unroll
    for (int i = 0; i < T; ++i) {
      float s = softplus_f(dv[i]);
      du[i]  = s * uv[i];
      spl[i] = s * LOG2E;              // exp2 arg = spl*A == sp*LOG2E*A
    }
  }

  float y[T];
  #pragma unroll
  for (int i = 0; i < T; ++i) y[i] = 0.0f;

  // Per-pass wave-total buffers: (a,x) per (wave, state). 4*8*4*8B = 1 KB.
  // Separate buffer per pass -> no end-of-pass barrier needed.
  __shared__ float2 sAX[NP][NW][NQ];

  #pragma unroll 1                      // passes sequential: live-range control
  for (int q = 0; q < NP; ++q) {
    // A quarter: uniform address -> scalar-load friendly. Raw values; LOG2E
    // already folded into spl[].
    float Aq[NQ];
    {
      const float4 av = *reinterpret_cast<const float4*>(A + (size_t)d * kN + q * NQ);
      Aq[0] = av.x; Aq[1] = av.y; Aq[2] = av.z; Aq[3] = av.w;
    }
    const float4* B4 = reinterpret_cast<const float4*>(Bm + ((size_t)b * kN + q * NQ) * kL);
    const float4* C4 = reinterpret_cast<const float4*>(Cm + ((size_t)b * kN + q * NQ) * kL);

    // ---- Pass A with the cp-trick: C consumed at load time.
    // h_i = pp_i*h0 + hl_i (linearity) =>  y_i += C_i*hl_i here,
    // cp_i = C_i*pp_i saved; post-scan apply is pure register FMA.
    // Loads at point of use (R0 form): the compiler hoists across the
    // unrolled n-loop as register slack allows — R1's explicit depth-1
    // prefetch pinned it to one tile in flight and regressed.
    float cp[NQ][T];
    float cA[NQ], cX[NQ];
    #pragma unroll
    for (int n = 0; n < NQ; ++n) {
      float4 b0 = B4[n * (kL / 4) + tid];
      float4 c0 = C4[n * (kL / 4) + tid];
      float Bv[T] = {b0.x, b0.y, b0.z, b0.w};
      float Cv[T] = {c0.x, c0.y, c0.z, c0.w};
      float h = 0.0f, p = 1.0f;
      #pragma unroll
      for (int i = 0; i < T; ++i) {
        float a = fast_exp2(spl[i] * Aq[n]);
        h = a * h + du[i] * Bv[i];
        p *= a;
        y[i] += Cv[i] * h;
        cp[n][i] = Cv[i] * p;
      }
      cA[n] = p; cX[n] = h;
    }

    // ---- Wave-level scan on chunk aggregates — raw DPP, 2 inst/state/step.
    {
      float x0=cX[0], x1=cX[1], x2=cX[2], x3=cX[3];
      float a0=cA[0], a1=cA[1], a2=cA[2], a3=cA[3];
      asm("s_nop 1\n\t"
          SCAN_STEP("row_shr:1 row_mask:0xf bank_mask:0xf")
          SCAN_STEP("row_shr:2 row_mask:0xf bank_mask:0xf")
          SCAN_STEP("row_shr:4 row_mask:0xf bank_mask:0xf")
          SCAN_STEP("row_shr:8 row_mask:0xf bank_mask:0xf")
          SCAN_STEP("row_bcast:15 row_mask:0xa bank_mask:0xf")
          SCAN_STEP("row_bcast:31 row_mask:0xc bank_mask:0xf")
          : "+v"(x0), "+v"(x1), "+v"(x2), "+v"(x3),
            "+v"(a0), "+v"(a1), "+v"(a2), "+v"(a3));
      cX[0]=x0; cX[1]=x1; cX[2]=x2; cX[3]=x3;
      cA[0]=a0; cA[1]=a1; cA[2]=a2; cA[3]=a3;
    }

    // ---- Publish wave totals (lane 63 holds them), ONE barrier.
    if (lane == 63) {
      #pragma unroll
      for (int n = 0; n < NQ; ++n) sAX[q][wid][n] = make_float2(cA[n], cX[n]);
    }
    __syncthreads();

    // ---- Parallel exclusive fold: all 7 candidate aggregates load
    // concurrently (one lgkm wait; 4-lane-group same-address broadcast =
    // conflict-free), then an identity-padded select+fma chain. wid is
    // wave-uniform. Order matches the serial loop:
    // ex = x[wid-1] + a[wid-1]*(x[wid-2] + ...), identities are no-ops.
    float ex = 0.0f;                     // lane n<4: exclusive x-prefix, state n
    {
      const int n = lane & (NQ - 1);
      float2 s[NW - 1];
      #pragma unroll
      for (int w2 = 0; w2 < NW - 1; ++w2) s[w2] = sAX[q][w2][n];
      #pragma unroll
      for (int w2 = 0; w2 < NW - 1; ++w2) {
        float aa = (w2 < wid) ? s[w2].x : 1.0f;
        float xx = (w2 < wid) ? s[w2].y : 0.0f;
        ex = aa * ex + xx;
      }
    }

    // ---- Apply: y_i += cp_i * h0   (pure FMA; exn broadcast via readlane)
    #pragma unroll
    for (int n = 0; n < NQ; ++n) {
      float al = dppf<0x138,0xF>(1.0f, cA[n]);   // lane-exclusive prefix
      float xl = dppf<0x138,0xF>(0.0f, cX[n]);
      float exn = readlane_f(ex, n);             // scalar: wave-exclusive x
      float h0 = al * exn + xl;                  // state entering this chunk
      #pragma unroll
      for (int i = 0; i < T; ++i) y[i] += cp[n][i] * h0;
    }
    // no end-of-pass barrier: each pass uses its own sAX buffer
  }

  // ---- Epilogue: + u*D, * silu(z), store  (u re-loaded here)
  const float Dd = Dv[d];
  const float4* z4 = reinterpret_cast<const float4*>(zm + roff);
  float4 z0 = z4[tid];
  float4 a0 = u4[tid];
  float zv[T] = {z0.x, z0.y, z0.z, z0.w};
  float uv[T] = {a0.x, a0.y, a0.z, a0.w};
  float ov[T];
  #pragma unroll
  for (int i = 0; i < T; ++i) {
    float yy  = y[i] + uv[i] * Dd;
    float sig = 1.0f / (1.0f + fast_exp(-zv[i]));
    ov[i] = yy * zv[i] * sig;
  }
  reinterpret_cast<float4*>(out + roff)[tid] = make_float4(ov[0], ov[1], ov[2], ov[3]);
}

extern "C" void kernel_launch(void* const* d_in, const int* in_sizes, int n_in,
                              void* d_out, int out_size, void* d_ws, size_t ws_size,
                              hipStream_t stream)
{
  const float* u  = (const float*)d_in[0];
  const float* dl = (const float*)d_in[1];
  const float* A  = (const float*)d_in[2];
  const float* Bm = (const float*)d_in[3];
  const float* Cm = (const float*)d_in[4];
  const float* Dv = (const float*)d_in[5];
  const float* zm = (const float*)d_in[6];
  float* out = (float*)d_out;
  const int rows = in_sizes[0] / kL;   // b*d = 2048
  selscan_kernel<<<rows, BLOCK, 0, stream>>>(u, dl, A, Bm, Cm, Dv, zm, out);
}

// Round 3
// 125.898 us; speedup vs baseline: 1.0986x; 1.0048x over previous
//
#include <hip/hip_runtime.h>
#include <cstdint>

// Shapes fixed by the harness:
// u, delta, z: (b=2, d=1024, l=2048) fp32; A: (d, n=16); B, C: (b, n, l); D: (d,)
constexpr int kD = 1024;
constexpr int kN = 16;
constexpr int kL = 2048;
constexpr int BLOCK = 512;
constexpr int T  = kL / BLOCK;   // 4 timesteps per thread (one float4)
constexpr int NW = BLOCK / 64;   // 8 waves per block
constexpr int NQ = 4;            // states per pass (quarter of kN)
constexpr int NP = kN / NQ;      // 4 passes
constexpr float LOG2E = 1.44269504088896340736f;

// s_waitcnt immediates (gfx9 encoding: vm[3:0]+[15:14], exp[6:4], lgkm[11:8])
constexpr unsigned WAIT_LGKM0 = 0xC07F;  // lgkmcnt(0); vmcnt/expcnt = no-wait
constexpr unsigned WAIT_VM0   = 0x0F70;  // vmcnt(0);   lgkm/expcnt  = no-wait

__device__ __forceinline__ float fast_exp2(float x) { return __builtin_amdgcn_exp2f(x); }
__device__ __forceinline__ float fast_exp(float x)  { return __builtin_amdgcn_exp2f(x * LOG2E); }
__device__ __forceinline__ float softplus_f(float x) {
  return (x > 20.0f) ? x : __logf(1.0f + fast_exp(x));
}

// Async global->LDS (16B/lane). Each thread stages ITS OWN float4 into its own
// LDS slot (dest = wave-uniform base + lane*16; lane0's pointer IS the wave
// base, so passing the per-lane slot pointer is correct). Self-staged,
// self-read => ordering is purely this wave's vmcnt: NO barrier, NO dbuf.
__device__ __forceinline__ void stage16(const float* g, float* l) {
  __builtin_amdgcn_global_load_lds(
      (const __attribute__((address_space(1))) void*)g,
      (__attribute__((address_space(3))) void*)l, 16, 0, 0);
}

// DPP move with explicit 'old' (identity) — used only for the lane-exclusive
// prefix in the apply phase.
template<int CTRL, int RM>
__device__ __forceinline__ float dppf(float old_, float src) {
  union U { float f; int i; };
  U o, s, r; o.f = old_; s.f = src;
  r.i = __builtin_amdgcn_update_dpp(o.i, s.i, CTRL, RM, 0xF, false);
  return r.f;
}

__device__ __forceinline__ float readlane_f(float v, int l) {
  union U { float f; int i; };
  U a, r; a.f = v;
  r.i = __builtin_amdgcn_readlane(a.i, l);
  return r.f;
}

// R12: hot 64-lane scan in raw DPP asm. bound_ctrl off + row_mask => invalid
// lanes DON'T WRITE dest, so in-place
//   v_fmac_f32_dpp x, x, a   (x += dpp(x)*a; boundary lanes keep x)
//   v_mul_f32_dpp  a, a, a   (a *= dpp(a);   boundary lanes keep a)
// is one masked Hillis-Steele step in 2 insts/state. State-inner interleave
// gives 8-inst spacing for the VALU->DPP hazard; s_nop 1 covers entry.
#define SCAN_FM(X, A, CTRL) \
  "v_fmac_f32_dpp " X ", " X ", " A " " CTRL "\n\t" \
  "v_mul_f32_dpp "  A ", " A ", " A " " CTRL "\n\t"
#define SCAN_STEP(CTRL) \
  SCAN_FM("%0","%4",CTRL) SCAN_FM("%1","%5",CTRL) \
  SCAN_FM("%2","%6",CTRL) SCAN_FM("%3","%7",CTRL)

// One selective-scan step for element i of a state: a = exp2(spl*A);
// h = a*h + du*B; p *= a; y += C*h; cp = C*p. Direct float4 components
// (no Bv[]/Cv[] staging arrays -> no chance of stray v_movs).
#define SSTEP(i, Bc, Cc) {                         \
    float a_ = fast_exp2(spl[i] * Arn);            \
    h = fmaf(a_, h, du[i] * (Bc));                 \
    p *= a_;                                       \
    y[i] = fmaf((Cc), h, y[i]);                    \
    cp[n][i] = (Cc) * p; }

// Single-arg launch_bounds ONLY: any min-waves hint triggers a spill cascade
// (R2: 48 VGPR + 350 MB scratch; R3: 64 VGPR + 260 MB; R6: 1024-thr cap).
// Occupancy raised STRUCTURALLY (R2 of this session): 4 passes of 4 states
// crossed the <=64-VGPR cliff -> 8 waves/SIMD, 4 blocks/CU. Keep VGPR <= 64!
__global__ __launch_bounds__(BLOCK)
void selscan_kernel(const float* __restrict__ u,  const float* __restrict__ dl,
                    const float* __restrict__ A,  const float* __restrict__ Bm,
                    const float* __restrict__ Cm, const float* __restrict__ Dv,
                    const float* __restrict__ zm, float* __restrict__ out)
{
  const int row  = blockIdx.x;          // b*kD + d
  const int b    = row >> 10;           // kD = 1024
  const int d    = row & (kD - 1);
  const int tid  = threadIdx.x;
  const int lane = tid & 63;
  const int wid  = tid >> 6;

  const size_t roff = (size_t)row * kL;
  const float4* u4 = reinterpret_cast<const float4*>(u  + roff);
  const float4* d4 = reinterpret_cast<const float4*>(dl + roff);
  const float4* B4all = reinterpret_cast<const float4*>(Bm + (size_t)b * kN * kL);
  const float4* C4all = reinterpret_cast<const float4*>(Cm + (size_t)b * kN * kL);

  // Staging buffer for each pass's FIRST TWO states' B/C tiles:
  // [B/C][state-in-pair][tid]. 32 KB/block; +sAX => 33 KB -> still 4 blocks/CU
  // (160/33). Single-buffered: pass q's reads retire (lgkm, consumed in
  // compute) long before pass q+1's DMA data lands (vm).
  __shared__ float4 stg[2][2][BLOCK];
  // Per-pass wave-total buffers: (a,x) per (wave, state). 4*8*4*8B = 1 KB.
  __shared__ float2 sAX[NP][NW][NQ];

  // u/delta loads FIRST, then pass-0 staging DMAs: softplus' wait on u/delta
  // is then a counted vmcnt that leaves the (younger) DMAs in flight.
  float4 a0 = u4[tid];
  float4 b0_ = d4[tid];
  stage16((const float*)&B4all[0 * (kL/4) + tid], (float*)&stg[0][0][tid]);
  stage16((const float*)&B4all[1 * (kL/4) + tid], (float*)&stg[0][1][tid]);
  stage16((const float*)&C4all[0 * (kL/4) + tid], (float*)&stg[1][0][tid]);
  stage16((const float*)&C4all[1 * (kL/4) + tid], (float*)&stg[1][1][tid]);

  // Per-thread chunk [tid*T, tid*T+T): softplus(delta)*LOG2E and delta*u in
  // regs. u itself is NOT carried — re-loaded in the epilogue.
  float spl[T], du[T];
  {
    float uv[T] = {a0.x, a0.y, a0.z, a0.w};
    float dv[T] = {b0_.x, b0_.y, b0_.z, b0_.w};
    #pragma unroll
    for (int i = 0; i < T; ++i) {
      float s = softplus_f(dv[i]);
      du[i]  = s * uv[i];
      spl[i] = s * LOG2E;              // exp2 arg = spl*A == sp*LOG2E*A
    }
  }

  float y[T];
  #pragma unroll
  for (int i = 0; i < T; ++i) y[i] = 0.0f;

  #pragma unroll 1                      // passes sequential: live-range control
  for (int q = 0; q < NP; ++q) {
    // A quarter: uniform address -> scalar-load friendly. LOG2E in spl[].
    float Aq[NQ];
    {
      const float4 av = *reinterpret_cast<const float4*>(A + (size_t)d * kN + q * NQ);
      Aq[0] = av.x; Aq[1] = av.y; Aq[2] = av.z; Aq[3] = av.w;
    }
    const float4* Bq = B4all + (size_t)(q * NQ) * (kL/4);
    const float4* Cq = C4all + (size_t)(q * NQ) * (kL/4);

    // Staged pair-0 has been in flight since the previous publish (prologue
    // for q=0) — the only outstanding vm ops at this point, so vmcnt(0) is
    // exact. sched_barrier pins the ds_reads below the wait (rule #18).
    __builtin_amdgcn_s_waitcnt(WAIT_VM0);
    __builtin_amdgcn_sched_barrier(0);

    // Pair-1 globals issued first (longest latency; hidden under pair-0
    // compute), then the staged pair-0 ds_read_b128s (16B/lane stride:
    // conflict-free).
    float4 b2 = Bq[2 * (kL/4) + tid];
    float4 c2 = Cq[2 * (kL/4) + tid];
    float4 b3 = Bq[3 * (kL/4) + tid];
    float4 c3 = Cq[3 * (kL/4) + tid];
    float4 b0 = stg[0][0][tid];
    float4 b1 = stg[0][1][tid];
    float4 c0 = stg[1][0][tid];
    float4 c1 = stg[1][1][tid];

    // ---- Pass A with the cp-trick: C consumed at load time.
    // h_i = pp_i*h0 + hl_i (linearity) =>  y_i += C_i*hl_i here,
    // cp_i = C_i*pp_i saved; post-scan apply is pure register FMA.
    float cp[NQ][T];
    float cA[NQ], cX[NQ];
    {
      { const int n = 0; const float Arn = Aq[0]; float h = 0.f, p = 1.f;
        SSTEP(0, b0.x, c0.x) SSTEP(1, b0.y, c0.y) SSTEP(2, b0.z, c0.z) SSTEP(3, b0.w, c0.w)
        cA[n] = p; cX[n] = h; }
      { const int n = 1; const float Arn = Aq[1]; float h = 0.f, p = 1.f;
        SSTEP(0, b1.x, c1.x) SSTEP(1, b1.y, c1.y) SSTEP(2, b1.z, c1.z) SSTEP(3, b1.w, c1.w)
        cA[n] = p; cX[n] = h; }
      { const int n = 2; const float Arn = Aq[2]; float h = 0.f, p = 1.f;
        SSTEP(0, b2.x, c2.x) SSTEP(1, b2.y, c2.y) SSTEP(2, b2.z, c2.z) SSTEP(3, b2.w, c2.w)
        cA[n] = p; cX[n] = h; }
      { const int n = 3; const float Arn = Aq[3]; float h = 0.f, p = 1.f;
        SSTEP(0, b3.x, c3.x) SSTEP(1, b3.y, c3.y) SSTEP(2, b3.z, c3.z) SSTEP(3, b3.w, c3.w)
        cA[n] = p; cX[n] = h; }
    }

    // ---- Wave-level scan on chunk aggregates — raw DPP, 2 inst/state/step.
    {
      float x0=cX[0], x1=cX[1], x2=cX[2], x3=cX[3];
      float a0_=cA[0], a1_=cA[1], a2_=cA[2], a3_=cA[3];
      asm("s_nop 1\n\t"
          SCAN_STEP("row_shr:1 row_mask:0xf bank_mask:0xf")
          SCAN_STEP("row_shr:2 row_mask:0xf bank_mask:0xf")
          SCAN_STEP("row_shr:4 row_mask:0xf bank_mask:0xf")
          SCAN_STEP("row_shr:8 row_mask:0xf bank_mask:0xf")
          SCAN_STEP("row_bcast:15 row_mask:0xa bank_mask:0xf")
          SCAN_STEP("row_bcast:31 row_mask:0xc bank_mask:0xf")
          : "+v"(x0), "+v"(x1), "+v"(x2), "+v"(x3),
            "+v"(a0_), "+v"(a1_), "+v"(a2_), "+v"(a3_));
      cX[0]=x0; cX[1]=x1; cX[2]=x2; cX[3]=x3;
      cA[0]=a0_; cA[1]=a1_; cA[2]=a2_; cA[3]=a3_;
    }

    // ---- Publish wave totals (lane 63 holds them).
    if (lane == 63) {
      #pragma unroll
      for (int n = 0; n < NQ; ++n) sAX[q][wid][n] = make_float2(cA[n], cX[n]);
    }

    // ---- Issue NEXT pass's pair-0 staging DMAs BEFORE the barrier: they fly
    // through fold+apply (and the barrier below does NOT drain vmcnt).
    if (q < NP - 1) {
      const float4* Bn = B4all + (size_t)((q + 1) * NQ) * (kL/4);
      const float4* Cn = C4all + (size_t)((q + 1) * NQ) * (kL/4);
      stage16((const float*)&Bn[0 * (kL/4) + tid], (float*)&stg[0][0][tid]);
      stage16((const float*)&Bn[1 * (kL/4) + tid], (float*)&stg[0][1][tid]);
      stage16((const float*)&Cn[0 * (kL/4) + tid], (float*)&stg[1][0][tid]);
      stage16((const float*)&Cn[1 * (kL/4) + tid], (float*)&stg[1][1][tid]);
    }

    // ---- Barrier WITHOUT vmcnt drain (raw s_barrier): lgkmcnt(0) makes the
    // sAX publish visible; the staging DMAs (vm-counted) stay in flight.
    __builtin_amdgcn_s_waitcnt(WAIT_LGKM0);
    __builtin_amdgcn_s_barrier();

    // ---- Parallel exclusive fold: all 7 candidate aggregates load
    // concurrently (one lgkm wait; 4-lane-group same-address broadcast =
    // conflict-free), then an identity-padded select+fma chain. wid is
    // wave-uniform. ex = x[wid-1] + a[wid-1]*(x[wid-2] + ...).
    float ex = 0.0f;                     // lane n<4: exclusive x-prefix, state n
    {
      const int n = lane & (NQ - 1);
      float2 s[NW - 1];
      #pragma unroll
      for (int w2 = 0; w2 < NW - 1; ++w2) s[w2] = sAX[q][w2][n];
      #pragma unroll
      for (int w2 = 0; w2 < NW - 1; ++w2) {
        float aa = (w2 < wid) ? s[w2].x : 1.0f;
        float xx = (w2 < wid) ? s[w2].y : 0.0f;
        ex = aa * ex + xx;
      }
    }

    // ---- Apply: y_i += cp_i * h0   (pure FMA; exn broadcast via readlane)
    #pragma unroll
    for (int n = 0; n < NQ; ++n) {
      float al = dppf<0x138,0xF>(1.0f, cA[n]);   // lane-exclusive prefix
      float xl = dppf<0x138,0xF>(0.0f, cX[n]);
      float exn = readlane_f(ex, n);             // scalar: wave-exclusive x
      float h0 = al * exn + xl;                  // state entering this chunk
      #pragma unroll
      for (int i = 0; i < T; ++i) y[i] += cp[n][i] * h0;
    }
    // no end-of-pass barrier: each pass uses its own sAX buffer; stg reuse is
    // safe within-wave (reads retired before next DMA lands).
  }

  // ---- Epilogue: + u*D, * silu(z), store  (u re-loaded here)
  const float Dd = Dv[d];
  const float4* z4 = reinterpret_cast<const float4*>(zm + roff);
  float4 z0 = z4[tid];
  float4 ua = u4[tid];
  float zv[T] = {z0.x, z0.y, z0.z, z0.w};
  float uv[T] = {ua.x, ua.y, ua.z, ua.w};
  float ov[T];
  #pragma unroll
  for (int i = 0; i < T; ++i) {
    float yy  = y[i] + uv[i] * Dd;
    float sig = 1.0f / (1.0f + fast_exp(-zv[i]));
    ov[i] = yy * zv[i] * sig;
  }
  reinterpret_cast<float4*>(out + roff)[tid] = make_float4(ov[0], ov[1], ov[2], ov[3]);
}

extern "C" void kernel_launch(void* const* d_in, const int* in_sizes, int n_in,
                              void* d_out, int out_size, void* d_ws, size_t ws_size,
                              hipStream_t stream)
{
  const float* u  = (const float*)d_in[0];
  const float* dl = (const float*)d_in[1];
  const float* A  = (const float*)d_in[2];
  const float* Bm = (const float*)d_in[3];
  const float* Cm = (const float*)d_in[4];
  const float* Dv = (const float*)d_in[5];
  const float* zm = (const float*)d_in[6];
  float* out = (float*)d_out;
  const int rows = in_sizes[0] / kL;   // b*d = 2048
  selscan_kernel<<<rows, BLOCK, 0, stream>>>(u, dl, A, Bm, Cm, Dv, zm, out);
}